// Round 10
// baseline (7012.690 us; speedup 1.0000x reference)
//
#include <hip/hip_runtime.h>
#include <cstdint>
#include <cstddef>

// B=2, S=2048, D=1024, H=16, HD=64. Inputs fp32, OUTPUT FP32 (pinned R8/R9:
// u16 probe invisible => harness reads float32; earlier bf16-output rounds were
// compared through a decimated bit-reinterpretation => all garbage).
// R10 = R4's audited literal-reference pipeline (x@W, interleaved RoPE, causal)
// with float32 output stores.
// ws (fp32): Q[4.19M] K[4.19M] V[4.19M] (b,h,s,hd) | ctx[4.19M] (b,s,D) = 64 MiB.
#define BB 2
#define SS 2048
#define DD 1024
#define HH 16
#define HDD 64

// ---- QKV projection, one thread per (b,h,s,pair); y = x @ W; interleaved RoPE ----
__global__ __launch_bounds__(256) void qkv_naive(
    const float* __restrict__ X, const float* __restrict__ W,
    float* __restrict__ out, const int doRope)
{
    const int t = blockIdx.x * 256 + threadIdx.x;   // 2^21 threads
    const int p = t & 31;                // pair index 0..31
    const int s = (t >> 5) & (SS - 1);   // seq row
    const int h = (t >> 16) & (HH - 1);  // head
    const int b = t >> 20;               // batch
    const int c0 = h * HDD + 2 * p;      // W column of even elem

    const float* xr = X + ((size_t)b * SS + s) * DD;
    float acc0 = 0.f, acc1 = 0.f;
    for (int k = 0; k < DD; k++) {
        const float xv = xr[k];
        acc0 = fmaf(xv, W[(size_t)k * DD + c0], acc0);
        acc1 = fmaf(xv, W[(size_t)k * DD + c0 + 1], acc1);
    }

    float r0 = acc0, r1 = acc1;
    if (doRope) {
        // inv_freq[p] = 10000^(-p/32) = 2^(-p * log2(10000)/32)
        const float inv = exp2f((float)p * -0.4152410118609203f);
        float sn, cs;
        sincosf((float)s * inv, &sn, &cs);
        r0 = acc0 * cs - acc1 * sn;
        r1 = acc0 * sn + acc1 * cs;
    }
    float* dst = out + (((size_t)(b * HH + h) * SS + s) * HDD + 2 * p);
    dst[0] = r0;
    dst[1] = r1;
}

// ---- Attention: one wave per (b,h,q). Literal two-pass causal softmax. ----
__global__ __launch_bounds__(64) void attn_naive(
    const float* __restrict__ Q, const float* __restrict__ K,
    const float* __restrict__ V, float* __restrict__ ctx)
{
    __shared__ float qrow[HDD];
    __shared__ float sc[SS];
    const int lane = threadIdx.x;        // 0..63
    const int q = blockIdx.x;
    const int bh = blockIdx.y;

    const float* Qr = Q + ((size_t)bh * SS + q) * HDD;
    qrow[lane] = Qr[lane] * 0.125f;      // fold 1/sqrt(64)
    __syncthreads();

    for (int j0 = 0; j0 <= q; j0 += 64) {
        const int j = j0 + lane;
        if (j <= q) {
            const float* Kr = K + ((size_t)bh * SS + j) * HDD;
            float sval = 0.f;
            for (int d = 0; d < HDD; d++)
                sval = fmaf(qrow[d], Kr[d], sval);
            sc[j] = sval;
        }
    }
    __syncthreads();

    float mm = -1e30f;
    for (int i = lane; i <= q; i += 64) mm = fmaxf(mm, sc[i]);
    #pragma unroll
    for (int off = 32; off; off >>= 1) mm = fmaxf(mm, __shfl_xor(mm, off));

    float lsum = 0.f;
    for (int i = lane; i <= q; i += 64) {
        const float pv = expf(sc[i] - mm);
        sc[i] = pv;
        lsum += pv;
    }
    #pragma unroll
    for (int off = 32; off; off >>= 1) lsum += __shfl_xor(lsum, off);
    __syncthreads();

    float accv = 0.f;
    for (int j = 0; j <= q; j++) {
        const float* Vr = V + ((size_t)bh * SS + j) * HDD;
        accv = fmaf(sc[j], Vr[lane], accv);
    }

    const int b = bh >> 4, h = bh & 15;
    ctx[((size_t)b * SS + q) * DD + h * HDD + lane] = accv / lsum;
}

// ---- Output projection, one thread per (m, n); out = ctx @ Wo, FP32 store ----
__global__ __launch_bounds__(256) void out_naive(
    const float* __restrict__ Xf, const float* __restrict__ W, float* __restrict__ out)
{
    const int t = blockIdx.x * 256 + threadIdx.x;   // 2^22 threads
    const int n = t & (DD - 1);
    const int m = t >> 10;
    const float* xr = Xf + (size_t)m * DD;
    float acc = 0.f;
    for (int k = 0; k < DD; k++)
        acc = fmaf(xr[k], W[(size_t)k * DD + n], acc);
    out[(size_t)m * DD + n] = acc;
}

extern "C" void kernel_launch(void* const* d_in, const int* in_sizes, int n_in,
                              void* d_out, int out_size, void* d_ws, size_t ws_size,
                              hipStream_t stream) {
    const float* x  = (const float*)d_in[0];
    const float* Wq = (const float*)d_in[1];
    const float* Wk = (const float*)d_in[2];
    const float* Wv = (const float*)d_in[3];
    const float* Wo = (const float*)d_in[4];
    float* out = (float*)d_out;

    const size_t qkv_elems = (size_t)BB * HH * SS * HDD;  // 4,194,304 fp32 each
    float* Qb  = (float*)d_ws;
    float* Kb  = Qb + qkv_elems;
    float* Vb  = Kb + qkv_elems;
    float* ctx = Vb + qkv_elems;   // total 64 MiB

    const int qkvThreads = BB * HH * SS * 32;   // 2,097,152
    hipLaunchKernelGGL(qkv_naive, dim3(qkvThreads / 256), dim3(256), 0, stream, x, Wq, Qb, 1);
    hipLaunchKernelGGL(qkv_naive, dim3(qkvThreads / 256), dim3(256), 0, stream, x, Wk, Kb, 1);
    hipLaunchKernelGGL(qkv_naive, dim3(qkvThreads / 256), dim3(256), 0, stream, x, Wv, Vb, 0);
    hipLaunchKernelGGL(attn_naive, dim3(SS, BB * HH), dim3(64), 0, stream, Qb, Kb, Vb, ctx);
    hipLaunchKernelGGL(out_naive, dim3((BB * SS * DD) / 256), dim3(256), 0, stream, ctx, Wo, out);
}

// Round 11
// 2964.208 us; speedup vs baseline: 2.3658x; 2.3658x over previous
//
#include <hip/hip_runtime.h>
#include <cstdint>
#include <cstddef>

// B=2, S=2048, D=1024, H=16, HD=64. Inputs fp32, output fp32 (pinned R10).
// R11: tiled fp32 GEMMs (64x64, BK=32, 4x4 microtile) + 4-wave LDS-tiled flash attn.
// ws (fp32): Q[4.19M] K[4.19M] V[4.19M] (b,h,s,hd) | ctx[4.19M] (b,s,D) = 64 MiB.
#define BB 2
#define SS 2048
#define DD 1024
#define HH 16
#define HDD 64

// ---------------- QKV projection GEMM (fp32 -> fp32, fused interleaved RoPE) ----------
// C(4096x1024) = X(4096x1024) @ W(1024x1024); out layout (b,h,s,hd).
__global__ __launch_bounds__(256) void gemm_qkv_rope(
    const float* __restrict__ X, const float* __restrict__ W,
    float* __restrict__ out, const int doRope)
{
    __shared__ float As[32][68];   // [k][m]
    __shared__ float Bs[32][68];   // [k][n]
    const int tid = threadIdx.x;
    const int m0 = blockIdx.y * 64;
    const int n0 = blockIdx.x * 64;
    const int tm = tid >> 4, tn = tid & 15;
    const int alr = tid >> 2;          // A row 0..63
    const int alc = (tid & 3) * 8;     // A k-col group (8 floats)
    const int bkr = tid >> 3;          // B k-row 0..31
    const int bnc = (tid & 7) * 8;     // B n-col group
    float acc[4][4] = {};

    for (int k0 = 0; k0 < DD; k0 += 32) {
        const float4 a0 = *(const float4*)&X[(size_t)(m0 + alr) * DD + k0 + alc];
        const float4 a1 = *(const float4*)&X[(size_t)(m0 + alr) * DD + k0 + alc + 4];
        const float4 b0 = *(const float4*)&W[(size_t)(k0 + bkr) * DD + n0 + bnc];
        const float4 b1 = *(const float4*)&W[(size_t)(k0 + bkr) * DD + n0 + bnc + 4];
        __syncthreads();
        As[alc + 0][alr] = a0.x; As[alc + 1][alr] = a0.y;
        As[alc + 2][alr] = a0.z; As[alc + 3][alr] = a0.w;
        As[alc + 4][alr] = a1.x; As[alc + 5][alr] = a1.y;
        As[alc + 6][alr] = a1.z; As[alc + 7][alr] = a1.w;
        Bs[bkr][bnc + 0] = b0.x; Bs[bkr][bnc + 1] = b0.y;
        Bs[bkr][bnc + 2] = b0.z; Bs[bkr][bnc + 3] = b0.w;
        Bs[bkr][bnc + 4] = b1.x; Bs[bkr][bnc + 5] = b1.y;
        Bs[bkr][bnc + 6] = b1.z; Bs[bkr][bnc + 7] = b1.w;
        __syncthreads();
        #pragma unroll
        for (int kk = 0; kk < 32; kk++) {
            const float4 a4 = *(const float4*)&As[kk][tm * 4];
            const float4 b4 = *(const float4*)&Bs[kk][tn * 4];
            const float ar[4] = {a4.x, a4.y, a4.z, a4.w};
            const float br[4] = {b4.x, b4.y, b4.z, b4.w};
            #pragma unroll
            for (int i = 0; i < 4; i++)
                #pragma unroll
                for (int j = 0; j < 4; j++)
                    acc[i][j] = fmaf(ar[i], br[j], acc[i][j]);
        }
    }

    const int h = blockIdx.x;          // 64-wide n-tile == one head
    const int hd0 = tn * 4;            // pairs hd0/2 and hd0/2+1 (interleaved)
    #pragma unroll
    for (int r = 0; r < 4; r++) {
        const int m = m0 + tm * 4 + r;
        const int b = m >> 11;
        const int srow = m & (SS - 1);
        float v0 = acc[r][0], v1 = acc[r][1], v2 = acc[r][2], v3 = acc[r][3];
        if (doRope) {
            // inv_freq[p] = 10000^(-p/32) = 2^(-p*log2(10000)/32)
            const float fs = (float)srow;
            const float inv0 = exp2f((float)(hd0 >> 1) * -0.4152410118609203f);
            const float inv1 = exp2f((float)((hd0 >> 1) + 1) * -0.4152410118609203f);
            float sn0, cs0, sn1, cs1;
            sincosf(fs * inv0, &sn0, &cs0);
            sincosf(fs * inv1, &sn1, &cs1);
            const float r0 = v0 * cs0 - v1 * sn0;
            const float r1 = v0 * sn0 + v1 * cs0;
            const float r2 = v2 * cs1 - v3 * sn1;
            const float r3 = v2 * sn1 + v3 * cs1;
            v0 = r0; v1 = r1; v2 = r2; v3 = r3;
        }
        *(float4*)&out[((size_t)(b * HH + h) * SS + srow) * HDD + hd0] =
            make_float4(v0, v1, v2, v3);
    }
}

// ---------------- Flash attention: 4 waves/block = 4 query rows, 64-key LDS tiles ------
__global__ __launch_bounds__(256) void attn_flash(
    const float* __restrict__ Q, const float* __restrict__ K,
    const float* __restrict__ V, float* __restrict__ ctx)
{
    __shared__ float Ks[64][65];   // stride 65: (row+col)%32 -> worst 2-way (free)
    __shared__ float Vs[64][65];
    const int tid = threadIdx.x;
    const int lane = tid & 63;
    const int w = tid >> 6;                 // wave id 0..3
    const int bh = blockIdx.y;              // b*16 + h
    const int qbase = blockIdx.x * 4;
    const int q = qbase + w;

    const float qd = Q[((size_t)bh * SS + q) * HDD + lane] * 0.125f; // fold 1/sqrt(64)
    float mrun = -1e30f, lrun = 0.f, accv = 0.f;

    const int r16 = tid >> 2;               // stage row 0..63
    const int c16 = (tid & 3) * 16;         // stage col base

    for (int j0 = 0; j0 <= qbase + 3; j0 += 64) {
        const float* kg = K + ((size_t)bh * SS + j0 + r16) * HDD + c16;
        const float* vg = V + ((size_t)bh * SS + j0 + r16) * HDD + c16;
        const float4 k0v = *(const float4*)(kg + 0);
        const float4 k1v = *(const float4*)(kg + 4);
        const float4 k2v = *(const float4*)(kg + 8);
        const float4 k3v = *(const float4*)(kg + 12);
        const float4 v0v = *(const float4*)(vg + 0);
        const float4 v1v = *(const float4*)(vg + 4);
        const float4 v2v = *(const float4*)(vg + 8);
        const float4 v3v = *(const float4*)(vg + 12);
        __syncthreads();
        {
            float* kr = &Ks[r16][c16];
            float* vr = &Vs[r16][c16];
            kr[0]  = k0v.x; kr[1]  = k0v.y; kr[2]  = k0v.z; kr[3]  = k0v.w;
            kr[4]  = k1v.x; kr[5]  = k1v.y; kr[6]  = k1v.z; kr[7]  = k1v.w;
            kr[8]  = k2v.x; kr[9]  = k2v.y; kr[10] = k2v.z; kr[11] = k2v.w;
            kr[12] = k3v.x; kr[13] = k3v.y; kr[14] = k3v.z; kr[15] = k3v.w;
            vr[0]  = v0v.x; vr[1]  = v0v.y; vr[2]  = v0v.z; vr[3]  = v0v.w;
            vr[4]  = v1v.x; vr[5]  = v1v.y; vr[6]  = v1v.z; vr[7]  = v1v.w;
            vr[8]  = v2v.x; vr[9]  = v2v.y; vr[10] = v2v.z; vr[11] = v2v.w;
            vr[12] = v3v.x; vr[13] = v3v.y; vr[14] = v3v.z; vr[15] = v3v.w;
        }
        __syncthreads();

        int nk = q - j0 + 1;                // wave-uniform, in [1,64] (see R0 audit)
        if (nk > 64) nk = 64;

        float s = 0.f;
        #pragma unroll
        for (int d = 0; d < 64; d++)
            s = fmaf(__shfl(qd, d), Ks[lane][d], s);
        if (lane >= nk) s = -1e30f;

        float mb = s;
        #pragma unroll
        for (int off = 32; off; off >>= 1)
            mb = fmaxf(mb, __shfl_xor(mb, off));
        const float mnew = fmaxf(mrun, mb);
        const float p = __expf(s - mnew);           // 0 for masked lanes
        const float alpha = __expf(mrun - mnew);
        float ls = p;
        #pragma unroll
        for (int off = 32; off; off >>= 1)
            ls += __shfl_xor(ls, off);
        lrun = lrun * alpha + ls;
        accv *= alpha;
        for (int j = 0; j < nk; j++)
            accv = fmaf(__shfl(p, j), Vs[j][lane], accv);
        mrun = mnew;
    }

    const int b = bh >> 4, h = bh & 15;
    ctx[((size_t)b * SS + q) * DD + h * HDD + lane] = accv / lrun;
}

// ---------------- Output projection: ctx @ Wo -> out (fp32) ----------------
__global__ __launch_bounds__(256) void gemm_out(
    const float* __restrict__ Xf, const float* __restrict__ W, float* __restrict__ out)
{
    __shared__ float As[32][68];
    __shared__ float Bs[32][68];
    const int tid = threadIdx.x;
    const int m0 = blockIdx.y * 64;
    const int n0 = blockIdx.x * 64;
    const int tm = tid >> 4, tn = tid & 15;
    const int alr = tid >> 2;
    const int alc = (tid & 3) * 8;
    const int bkr = tid >> 3;
    const int bnc = (tid & 7) * 8;
    float acc[4][4] = {};

    for (int k0 = 0; k0 < DD; k0 += 32) {
        const float4 a0 = *(const float4*)&Xf[(size_t)(m0 + alr) * DD + k0 + alc];
        const float4 a1 = *(const float4*)&Xf[(size_t)(m0 + alr) * DD + k0 + alc + 4];
        const float4 b0 = *(const float4*)&W[(size_t)(k0 + bkr) * DD + n0 + bnc];
        const float4 b1 = *(const float4*)&W[(size_t)(k0 + bkr) * DD + n0 + bnc + 4];
        __syncthreads();
        As[alc + 0][alr] = a0.x; As[alc + 1][alr] = a0.y;
        As[alc + 2][alr] = a0.z; As[alc + 3][alr] = a0.w;
        As[alc + 4][alr] = a1.x; As[alc + 5][alr] = a1.y;
        As[alc + 6][alr] = a1.z; As[alc + 7][alr] = a1.w;
        Bs[bkr][bnc + 0] = b0.x; Bs[bkr][bnc + 1] = b0.y;
        Bs[bkr][bnc + 2] = b0.z; Bs[bkr][bnc + 3] = b0.w;
        Bs[bkr][bnc + 4] = b1.x; Bs[bkr][bnc + 5] = b1.y;
        Bs[bkr][bnc + 6] = b1.z; Bs[bkr][bnc + 7] = b1.w;
        __syncthreads();
        #pragma unroll
        for (int kk = 0; kk < 32; kk++) {
            const float4 a4 = *(const float4*)&As[kk][tm * 4];
            const float4 b4 = *(const float4*)&Bs[kk][tn * 4];
            const float ar[4] = {a4.x, a4.y, a4.z, a4.w};
            const float br[4] = {b4.x, b4.y, b4.z, b4.w};
            #pragma unroll
            for (int i = 0; i < 4; i++)
                #pragma unroll
                for (int j = 0; j < 4; j++)
                    acc[i][j] = fmaf(ar[i], br[j], acc[i][j]);
        }
    }

    #pragma unroll
    for (int r = 0; r < 4; r++) {
        const int m = m0 + tm * 4 + r;
        *(float4*)&out[(size_t)m * DD + n0 + tn * 4] =
            make_float4(acc[r][0], acc[r][1], acc[r][2], acc[r][3]);
    }
}

extern "C" void kernel_launch(void* const* d_in, const int* in_sizes, int n_in,
                              void* d_out, int out_size, void* d_ws, size_t ws_size,
                              hipStream_t stream) {
    const float* x  = (const float*)d_in[0];
    const float* Wq = (const float*)d_in[1];
    const float* Wk = (const float*)d_in[2];
    const float* Wv = (const float*)d_in[3];
    const float* Wo = (const float*)d_in[4];
    float* out = (float*)d_out;

    const size_t qkv_elems = (size_t)BB * HH * SS * HDD;  // 4,194,304 fp32 each
    float* Qb  = (float*)d_ws;
    float* Kb  = Qb + qkv_elems;
    float* Vb  = Kb + qkv_elems;
    float* ctx = Vb + qkv_elems;   // total 64 MiB

    dim3 gg(DD / 64, (BB * SS) / 64), bb(256);  // (16, 64) x 256
    hipLaunchKernelGGL(gemm_qkv_rope, gg, bb, 0, stream, x, Wq, Qb, 1);
    hipLaunchKernelGGL(gemm_qkv_rope, gg, bb, 0, stream, x, Wk, Kb, 1);
    hipLaunchKernelGGL(gemm_qkv_rope, gg, bb, 0, stream, x, Wv, Vb, 0);
    hipLaunchKernelGGL(attn_flash, dim3(SS / 4, BB * HH), bb, 0, stream, Qb, Kb, Vb, ctx);
    hipLaunchKernelGGL(gemm_out, gg, bb, 0, stream, ctx, Wo, out);
}

// Round 12
// 1416.588 us; speedup vs baseline: 4.9504x; 2.0925x over previous
//
#include <hip/hip_runtime.h>
#include <cstdint>
#include <cstddef>

// B=2, S=2048, D=1024, H=16, HD=64. Inputs fp32, output fp32 (pinned R10).
// R12: attention restructured as register-blocked GEMM (4x4 microtile, 64x64
// S-tiles, online softmax, P via LDS transpose). GEMMs unchanged from R11.
// ws (fp32): Q[4.19M] K[4.19M] V[4.19M] (b,h,s,hd) | ctx[4.19M] (b,s,D) = 64 MiB.
#define BB 2
#define SS 2048
#define DD 1024
#define HH 16
#define HDD 64

// ---------------- QKV projection GEMM (fp32 -> fp32, fused interleaved RoPE) ----------
__global__ __launch_bounds__(256) void gemm_qkv_rope(
    const float* __restrict__ X, const float* __restrict__ W,
    float* __restrict__ out, const int doRope)
{
    __shared__ float As[32][68];   // [k][m]
    __shared__ float Bs[32][68];   // [k][n]
    const int tid = threadIdx.x;
    const int m0 = blockIdx.y * 64;
    const int n0 = blockIdx.x * 64;
    const int tm = tid >> 4, tn = tid & 15;
    const int alr = tid >> 2;
    const int alc = (tid & 3) * 8;
    const int bkr = tid >> 3;
    const int bnc = (tid & 7) * 8;
    float acc[4][4] = {};

    for (int k0 = 0; k0 < DD; k0 += 32) {
        const float4 a0 = *(const float4*)&X[(size_t)(m0 + alr) * DD + k0 + alc];
        const float4 a1 = *(const float4*)&X[(size_t)(m0 + alr) * DD + k0 + alc + 4];
        const float4 b0 = *(const float4*)&W[(size_t)(k0 + bkr) * DD + n0 + bnc];
        const float4 b1 = *(const float4*)&W[(size_t)(k0 + bkr) * DD + n0 + bnc + 4];
        __syncthreads();
        As[alc + 0][alr] = a0.x; As[alc + 1][alr] = a0.y;
        As[alc + 2][alr] = a0.z; As[alc + 3][alr] = a0.w;
        As[alc + 4][alr] = a1.x; As[alc + 5][alr] = a1.y;
        As[alc + 6][alr] = a1.z; As[alc + 7][alr] = a1.w;
        Bs[bkr][bnc + 0] = b0.x; Bs[bkr][bnc + 1] = b0.y;
        Bs[bkr][bnc + 2] = b0.z; Bs[bkr][bnc + 3] = b0.w;
        Bs[bkr][bnc + 4] = b1.x; Bs[bkr][bnc + 5] = b1.y;
        Bs[bkr][bnc + 6] = b1.z; Bs[bkr][bnc + 7] = b1.w;
        __syncthreads();
        #pragma unroll
        for (int kk = 0; kk < 32; kk++) {
            const float4 a4 = *(const float4*)&As[kk][tm * 4];
            const float4 b4 = *(const float4*)&Bs[kk][tn * 4];
            const float ar[4] = {a4.x, a4.y, a4.z, a4.w};
            const float br[4] = {b4.x, b4.y, b4.z, b4.w};
            #pragma unroll
            for (int i = 0; i < 4; i++)
                #pragma unroll
                for (int j = 0; j < 4; j++)
                    acc[i][j] = fmaf(ar[i], br[j], acc[i][j]);
        }
    }

    const int h = blockIdx.x;
    const int hd0 = tn * 4;
    #pragma unroll
    for (int r = 0; r < 4; r++) {
        const int m = m0 + tm * 4 + r;
        const int b = m >> 11;
        const int srow = m & (SS - 1);
        float v0 = acc[r][0], v1 = acc[r][1], v2 = acc[r][2], v3 = acc[r][3];
        if (doRope) {
            const float fs = (float)srow;
            const float inv0 = exp2f((float)(hd0 >> 1) * -0.4152410118609203f);
            const float inv1 = exp2f((float)((hd0 >> 1) + 1) * -0.4152410118609203f);
            float sn0, cs0, sn1, cs1;
            sincosf(fs * inv0, &sn0, &cs0);
            sincosf(fs * inv1, &sn1, &cs1);
            const float r0 = v0 * cs0 - v1 * sn0;
            const float r1 = v0 * sn0 + v1 * cs0;
            const float r2 = v2 * cs1 - v3 * sn1;
            const float r3 = v2 * sn1 + v3 * cs1;
            v0 = r0; v1 = r1; v2 = r2; v3 = r3;
        }
        *(float4*)&out[((size_t)(b * HH + h) * SS + srow) * HDD + hd0] =
            make_float4(v0, v1, v2, v3);
    }
}

// -------- Attention: 64-query tile per block, GEMM-microtile QK^T and PV --------------
// Qs/Ks transposed [d][row], Vs natural [key][d], Ps transposed [key][q].
__global__ __launch_bounds__(256) void attn_tile(
    const float* __restrict__ Q, const float* __restrict__ K,
    const float* __restrict__ V, float* __restrict__ ctx)
{
    __shared__ float Qs[64][65];
    __shared__ float Ks[64][65];
    __shared__ float Vs[64][65];
    __shared__ float Ps[64][65];
    const int tid = threadIdx.x;
    const int tm = tid >> 4, tn = tid & 15;
    const int bh = blockIdx.y;
    const int q0 = (gridDim.x - 1 - blockIdx.x) * 64;  // heavy blocks first

    const int sr = tid >> 2;            // stage row 0..63
    const int sc = (tid & 3) * 16;      // stage col base

    // stage Q transposed + scaled (once)
    {
        const float* qg = Q + ((size_t)bh * SS + q0 + sr) * HDD + sc;
        #pragma unroll
        for (int i = 0; i < 4; i++) {
            const float4 v = *(const float4*)(qg + 4 * i);
            Qs[sc + 4 * i + 0][sr] = v.x * 0.125f;
            Qs[sc + 4 * i + 1][sr] = v.y * 0.125f;
            Qs[sc + 4 * i + 2][sr] = v.z * 0.125f;
            Qs[sc + 4 * i + 3][sr] = v.w * 0.125f;
        }
    }

    float O[4][4] = {};
    float mrun[4] = {-1e30f, -1e30f, -1e30f, -1e30f};
    float lrun[4] = {};

    for (int j0 = 0; j0 <= q0; j0 += 64) {
        // load K (transposed) and V (natural) tiles
        const float* kg = K + ((size_t)bh * SS + j0 + sr) * HDD + sc;
        const float* vg = V + ((size_t)bh * SS + j0 + sr) * HDD + sc;
        float4 kv[4], vv[4];
        #pragma unroll
        for (int i = 0; i < 4; i++) kv[i] = *(const float4*)(kg + 4 * i);
        #pragma unroll
        for (int i = 0; i < 4; i++) vv[i] = *(const float4*)(vg + 4 * i);
        __syncthreads();   // previous PV done (Vs/Ps free), Qs staged
        #pragma unroll
        for (int i = 0; i < 4; i++) {
            Ks[sc + 4 * i + 0][sr] = kv[i].x;
            Ks[sc + 4 * i + 1][sr] = kv[i].y;
            Ks[sc + 4 * i + 2][sr] = kv[i].z;
            Ks[sc + 4 * i + 3][sr] = kv[i].w;
            *(float4*)&Vs[sr][sc + 4 * i] = vv[i];
        }
        __syncthreads();

        // S = Q-tile @ K-tile^T  (reduce over d)
        float s[4][4] = {};
        #pragma unroll 16
        for (int d = 0; d < 64; d++) {
            const float4 a4 = *(const float4*)&Qs[d][tm * 4];
            const float4 b4 = *(const float4*)&Ks[d][tn * 4];
            const float ar[4] = {a4.x, a4.y, a4.z, a4.w};
            const float br[4] = {b4.x, b4.y, b4.z, b4.w};
            #pragma unroll
            for (int i = 0; i < 4; i++)
                #pragma unroll
                for (int j = 0; j < 4; j++)
                    s[i][j] = fmaf(ar[i], br[j], s[i][j]);
        }

        // causal mask (only the diagonal tile needs it)
        if (j0 == q0) {
            #pragma unroll
            for (int i = 0; i < 4; i++)
                #pragma unroll
                for (int j = 0; j < 4; j++)
                    if (tn * 4 + j > tm * 4 + i) s[i][j] = -1e30f;
        }

        // online softmax; row-group = 16 lanes (same lane>>4) of one wave
        float p[4][4];
        #pragma unroll
        for (int i = 0; i < 4; i++) {
            float mt = fmaxf(fmaxf(s[i][0], s[i][1]), fmaxf(s[i][2], s[i][3]));
            #pragma unroll
            for (int off = 1; off < 16; off <<= 1)
                mt = fmaxf(mt, __shfl_xor(mt, off));
            const float mnew = fmaxf(mrun[i], mt);
            const float alpha = __expf(mrun[i] - mnew);
            float ls = 0.f;
            #pragma unroll
            for (int j = 0; j < 4; j++) {
                p[i][j] = __expf(s[i][j] - mnew);
                ls += p[i][j];
            }
            #pragma unroll
            for (int off = 1; off < 16; off <<= 1)
                ls += __shfl_xor(ls, off);
            lrun[i] = lrun[i] * alpha + ls;
            mrun[i] = mnew;
            #pragma unroll
            for (int j = 0; j < 4; j++) O[i][j] *= alpha;
        }

        // write P transposed: Ps[key][q]
        #pragma unroll
        for (int j = 0; j < 4; j++)
            *(float4*)&Ps[tn * 4 + j][tm * 4] =
                make_float4(p[0][j], p[1][j], p[2][j], p[3][j]);
        __syncthreads();

        // O += P-tile @ V-tile  (reduce over keys)
        #pragma unroll 16
        for (int k = 0; k < 64; k++) {
            const float4 a4 = *(const float4*)&Ps[k][tm * 4];
            const float4 b4 = *(const float4*)&Vs[k][tn * 4];
            const float ar[4] = {a4.x, a4.y, a4.z, a4.w};
            const float br[4] = {b4.x, b4.y, b4.z, b4.w};
            #pragma unroll
            for (int i = 0; i < 4; i++)
                #pragma unroll
                for (int j = 0; j < 4; j++)
                    O[i][j] = fmaf(ar[i], br[j], O[i][j]);
        }
    }

    const int b = bh >> 4, h = bh & 15;
    #pragma unroll
    for (int i = 0; i < 4; i++) {
        const float inv = 1.f / lrun[i];
        const int row = q0 + tm * 4 + i;
        *(float4*)&ctx[((size_t)b * SS + row) * DD + h * HDD + tn * 4] =
            make_float4(O[i][0] * inv, O[i][1] * inv, O[i][2] * inv, O[i][3] * inv);
    }
}

// ---------------- Output projection: ctx @ Wo -> out (fp32) ----------------
__global__ __launch_bounds__(256) void gemm_out(
    const float* __restrict__ Xf, const float* __restrict__ W, float* __restrict__ out)
{
    __shared__ float As[32][68];
    __shared__ float Bs[32][68];
    const int tid = threadIdx.x;
    const int m0 = blockIdx.y * 64;
    const int n0 = blockIdx.x * 64;
    const int tm = tid >> 4, tn = tid & 15;
    const int alr = tid >> 2;
    const int alc = (tid & 3) * 8;
    const int bkr = tid >> 3;
    const int bnc = (tid & 7) * 8;
    float acc[4][4] = {};

    for (int k0 = 0; k0 < DD; k0 += 32) {
        const float4 a0 = *(const float4*)&Xf[(size_t)(m0 + alr) * DD + k0 + alc];
        const float4 a1 = *(const float4*)&Xf[(size_t)(m0 + alr) * DD + k0 + alc + 4];
        const float4 b0 = *(const float4*)&W[(size_t)(k0 + bkr) * DD + n0 + bnc];
        const float4 b1 = *(const float4*)&W[(size_t)(k0 + bkr) * DD + n0 + bnc + 4];
        __syncthreads();
        As[alc + 0][alr] = a0.x; As[alc + 1][alr] = a0.y;
        As[alc + 2][alr] = a0.z; As[alc + 3][alr] = a0.w;
        As[alc + 4][alr] = a1.x; As[alc + 5][alr] = a1.y;
        As[alc + 6][alr] = a1.z; As[alc + 7][alr] = a1.w;
        Bs[bkr][bnc + 0] = b0.x; Bs[bkr][bnc + 1] = b0.y;
        Bs[bkr][bnc + 2] = b0.z; Bs[bkr][bnc + 3] = b0.w;
        Bs[bkr][bnc + 4] = b1.x; Bs[bkr][bnc + 5] = b1.y;
        Bs[bkr][bnc + 6] = b1.z; Bs[bkr][bnc + 7] = b1.w;
        __syncthreads();
        #pragma unroll
        for (int kk = 0; kk < 32; kk++) {
            const float4 a4 = *(const float4*)&As[kk][tm * 4];
            const float4 b4 = *(const float4*)&Bs[kk][tn * 4];
            const float ar[4] = {a4.x, a4.y, a4.z, a4.w};
            const float br[4] = {b4.x, b4.y, b4.z, b4.w};
            #pragma unroll
            for (int i = 0; i < 4; i++)
                #pragma unroll
                for (int j = 0; j < 4; j++)
                    acc[i][j] = fmaf(ar[i], br[j], acc[i][j]);
        }
    }

    #pragma unroll
    for (int r = 0; r < 4; r++) {
        const int m = m0 + tm * 4 + r;
        *(float4*)&out[(size_t)m * DD + n0 + tn * 4] =
            make_float4(acc[r][0], acc[r][1], acc[r][2], acc[r][3]);
    }
}

extern "C" void kernel_launch(void* const* d_in, const int* in_sizes, int n_in,
                              void* d_out, int out_size, void* d_ws, size_t ws_size,
                              hipStream_t stream) {
    const float* x  = (const float*)d_in[0];
    const float* Wq = (const float*)d_in[1];
    const float* Wk = (const float*)d_in[2];
    const float* Wv = (const float*)d_in[3];
    const float* Wo = (const float*)d_in[4];
    float* out = (float*)d_out;

    const size_t qkv_elems = (size_t)BB * HH * SS * HDD;  // 4,194,304 fp32 each
    float* Qb  = (float*)d_ws;
    float* Kb  = Qb + qkv_elems;
    float* Vb  = Kb + qkv_elems;
    float* ctx = Vb + qkv_elems;   // total 64 MiB

    dim3 gg(DD / 64, (BB * SS) / 64), bb(256);
    hipLaunchKernelGGL(gemm_qkv_rope, gg, bb, 0, stream, x, Wq, Qb, 1);
    hipLaunchKernelGGL(gemm_qkv_rope, gg, bb, 0, stream, x, Wk, Kb, 1);
    hipLaunchKernelGGL(gemm_qkv_rope, gg, bb, 0, stream, x, Wv, Vb, 0);
    hipLaunchKernelGGL(attn_tile, dim3(SS / 64, BB * HH), bb, 0, stream, Qb, Kb, Vb, ctx);
    hipLaunchKernelGGL(gemm_out, gg, bb, 0, stream, ctx, Wo, out);
}

// Round 13
// 699.289 us; speedup vs baseline: 10.0283x; 2.0258x over previous
//
#include <hip/hip_runtime.h>
#include <cstdint>
#include <cstddef>

// B=2, S=2048, D=1024, H=16, HD=64. Inputs fp32, output fp32 (pinned R10).
// R13: MFMA attention (bf16 Q/K/V/P, fp32 acc). QKV GEMMs emit bf16; V-GEMM
// writes V^T via LDS-transposed epilogue. Output GEMM unchanged fp32.
// ws: Qb/Kb bf16 [bh][s][64] (8.4MB ea) | Vt bf16 [bh][64][s] | ctx fp32 [b,s,D].
#define BB 2
#define SS 2048
#define DD 1024
#define HH 16
#define HDD 64

typedef unsigned short u16;
typedef unsigned int u32;
typedef __attribute__((ext_vector_type(8))) short bf16x8;
typedef __attribute__((ext_vector_type(4))) float f32x4;

__device__ __forceinline__ u16 f2bf(float f) {
    union { float f; u32 u; } c; c.f = f;
    u32 r = c.u + 0x7fffu + ((c.u >> 16) & 1u);  // RNE
    return (u16)(r >> 16);
}

// ---------------- QKV projection GEMM -> bf16 rows, fused interleaved RoPE ------------
// scale folded into output (Q: 0.125). out[(b*16+h)*2048 + s][d] bf16.
__global__ __launch_bounds__(256) void gemm_qk_bf16(
    const float* __restrict__ X, const float* __restrict__ W,
    u16* __restrict__ out, const float scale)
{
    __shared__ float As[32][68];
    __shared__ float Bs[32][68];
    const int tid = threadIdx.x;
    const int m0 = blockIdx.y * 64;
    const int n0 = blockIdx.x * 64;
    const int tm = tid >> 4, tn = tid & 15;
    const int alr = tid >> 2;
    const int alc = (tid & 3) * 8;
    const int bkr = tid >> 3;
    const int bnc = (tid & 7) * 8;
    float acc[4][4] = {};

    for (int k0 = 0; k0 < DD; k0 += 32) {
        const float4 a0 = *(const float4*)&X[(size_t)(m0 + alr) * DD + k0 + alc];
        const float4 a1 = *(const float4*)&X[(size_t)(m0 + alr) * DD + k0 + alc + 4];
        const float4 b0 = *(const float4*)&W[(size_t)(k0 + bkr) * DD + n0 + bnc];
        const float4 b1 = *(const float4*)&W[(size_t)(k0 + bkr) * DD + n0 + bnc + 4];
        __syncthreads();
        As[alc + 0][alr] = a0.x; As[alc + 1][alr] = a0.y;
        As[alc + 2][alr] = a0.z; As[alc + 3][alr] = a0.w;
        As[alc + 4][alr] = a1.x; As[alc + 5][alr] = a1.y;
        As[alc + 6][alr] = a1.z; As[alc + 7][alr] = a1.w;
        Bs[bkr][bnc + 0] = b0.x; Bs[bkr][bnc + 1] = b0.y;
        Bs[bkr][bnc + 2] = b0.z; Bs[bkr][bnc + 3] = b0.w;
        Bs[bkr][bnc + 4] = b1.x; Bs[bkr][bnc + 5] = b1.y;
        Bs[bkr][bnc + 6] = b1.z; Bs[bkr][bnc + 7] = b1.w;
        __syncthreads();
        #pragma unroll
        for (int kk = 0; kk < 32; kk++) {
            const float4 a4 = *(const float4*)&As[kk][tm * 4];
            const float4 b4 = *(const float4*)&Bs[kk][tn * 4];
            const float ar[4] = {a4.x, a4.y, a4.z, a4.w};
            const float br[4] = {b4.x, b4.y, b4.z, b4.w};
            #pragma unroll
            for (int i = 0; i < 4; i++)
                #pragma unroll
                for (int j = 0; j < 4; j++)
                    acc[i][j] = fmaf(ar[i], br[j], acc[i][j]);
        }
    }

    const int h = blockIdx.x;
    const int hd0 = tn * 4;
    #pragma unroll
    for (int r = 0; r < 4; r++) {
        const int m = m0 + tm * 4 + r;
        const int b = m >> 11;
        const int srow = m & (SS - 1);
        float v0 = acc[r][0], v1 = acc[r][1], v2 = acc[r][2], v3 = acc[r][3];
        {   // interleaved RoPE
            const float fs = (float)srow;
            const float inv0 = exp2f((float)(hd0 >> 1) * -0.4152410118609203f);
            const float inv1 = exp2f((float)((hd0 >> 1) + 1) * -0.4152410118609203f);
            float sn0, cs0, sn1, cs1;
            sincosf(fs * inv0, &sn0, &cs0);
            sincosf(fs * inv1, &sn1, &cs1);
            const float r0 = v0 * cs0 - v1 * sn0;
            const float r1 = v0 * sn0 + v1 * cs0;
            const float r2 = v2 * cs1 - v3 * sn1;
            const float r3 = v2 * sn1 + v3 * cs1;
            v0 = r0; v1 = r1; v2 = r2; v3 = r3;
        }
        ushort4 o;
        o.x = f2bf(v0 * scale); o.y = f2bf(v1 * scale);
        o.z = f2bf(v2 * scale); o.w = f2bf(v3 * scale);
        *(ushort4*)&out[((size_t)(b * HH + h) * SS + srow) * HDD + hd0] = o;
    }
}

// ---------------- V projection GEMM -> bf16 V^T [bh][d][s] (no RoPE) -------------------
__global__ __launch_bounds__(256) void gemm_v_t(
    const float* __restrict__ X, const float* __restrict__ W, u16* __restrict__ outT)
{
    __shared__ float As[32][68];
    __shared__ float Bs[32][68];
    __shared__ float Ts[64][65];
    const int tid = threadIdx.x;
    const int m0 = blockIdx.y * 64;
    const int n0 = blockIdx.x * 64;
    const int tm = tid >> 4, tn = tid & 15;
    const int alr = tid >> 2;
    const int alc = (tid & 3) * 8;
    const int bkr = tid >> 3;
    const int bnc = (tid & 7) * 8;
    float acc[4][4] = {};

    for (int k0 = 0; k0 < DD; k0 += 32) {
        const float4 a0 = *(const float4*)&X[(size_t)(m0 + alr) * DD + k0 + alc];
        const float4 a1 = *(const float4*)&X[(size_t)(m0 + alr) * DD + k0 + alc + 4];
        const float4 b0 = *(const float4*)&W[(size_t)(k0 + bkr) * DD + n0 + bnc];
        const float4 b1 = *(const float4*)&W[(size_t)(k0 + bkr) * DD + n0 + bnc + 4];
        __syncthreads();
        As[alc + 0][alr] = a0.x; As[alc + 1][alr] = a0.y;
        As[alc + 2][alr] = a0.z; As[alc + 3][alr] = a0.w;
        As[alc + 4][alr] = a1.x; As[alc + 5][alr] = a1.y;
        As[alc + 6][alr] = a1.z; As[alc + 7][alr] = a1.w;
        Bs[bkr][bnc + 0] = b0.x; Bs[bkr][bnc + 1] = b0.y;
        Bs[bkr][bnc + 2] = b0.z; Bs[bkr][bnc + 3] = b0.w;
        Bs[bkr][bnc + 4] = b1.x; Bs[bkr][bnc + 5] = b1.y;
        Bs[bkr][bnc + 6] = b1.z; Bs[bkr][bnc + 7] = b1.w;
        __syncthreads();
        #pragma unroll
        for (int kk = 0; kk < 32; kk++) {
            const float4 a4 = *(const float4*)&As[kk][tm * 4];
            const float4 b4 = *(const float4*)&Bs[kk][tn * 4];
            const float ar[4] = {a4.x, a4.y, a4.z, a4.w};
            const float br[4] = {b4.x, b4.y, b4.z, b4.w};
            #pragma unroll
            for (int i = 0; i < 4; i++)
                #pragma unroll
                for (int j = 0; j < 4; j++)
                    acc[i][j] = fmaf(ar[i], br[j], acc[i][j]);
        }
    }

    // transpose epilogue: Ts[d_local][s_local]
    #pragma unroll
    for (int r = 0; r < 4; r++)
        #pragma unroll
        for (int j = 0; j < 4; j++)
            Ts[tn * 4 + j][tm * 4 + r] = acc[r][j];
    __syncthreads();

    const int h = blockIdx.x;
    const int b = m0 >> 11;
    const int s0 = m0 & (SS - 1);
    #pragma unroll
    for (int i = 0; i < 2; i++) {
        const int idx = tid + 256 * i;
        const int drow = idx >> 3;
        const int sch = (idx & 7) * 8;
        const float4 v0 = *(const float4*)&Ts[drow][sch];
        const float4 v1 = *(const float4*)&Ts[drow][sch + 4];
        uint4 o;
        o.x = (u32)f2bf(v0.x) | ((u32)f2bf(v0.y) << 16);
        o.y = (u32)f2bf(v0.z) | ((u32)f2bf(v0.w) << 16);
        o.z = (u32)f2bf(v1.x) | ((u32)f2bf(v1.y) << 16);
        o.w = (u32)f2bf(v1.z) | ((u32)f2bf(v1.w) << 16);
        *(uint4*)&outT[((size_t)(b * HH + h) * HDD + drow) * SS + s0 + sch] = o;
    }
}

// ---------------- MFMA flash attention: 64-q tile, 4 waves x 16 rows ------------------
__global__ __launch_bounds__(256) void attn_mfma(
    const u16* __restrict__ Qb, const u16* __restrict__ Kb,
    const u16* __restrict__ Vt, float* __restrict__ ctx)
{
    __shared__ u16 Ks[64][72];      // [key][d]
    __shared__ u16 Vs[64][72];      // [d][key]  (from V^T)
    __shared__ u16 Ps[4][16][72];   // per-wave [q][key]
    const int tid = threadIdx.x;
    const int lane = tid & 63;
    const int w = tid >> 6;
    const int li = lane & 15;
    const int quad = lane >> 4;
    const int bh = blockIdx.y;
    const int q0 = (gridDim.x - 1 - blockIdx.x) * 64;   // heavy blocks first

    // Q A-fragments (held all kernel): A[q=li][d=quad*8+j (+32)]
    bf16x8 aQ0, aQ1;
    {
        const u16* qg = Qb + ((size_t)bh * SS + q0 + 16 * w + li) * HDD + quad * 8;
        aQ0 = *(const bf16x8*)qg;
        aQ1 = *(const bf16x8*)(qg + 32);
    }

    f32x4 O[4] = {};                       // [d-subtile]; elem r = q-row quad*4+r
    float m_r[4] = {-1e30f, -1e30f, -1e30f, -1e30f};
    float l_r[4] = {};

    const int ntiles = (q0 >> 6) + 1;
    const int krow = tid >> 3;             // staging row 0..31
    const int kch = (tid & 7) * 8;         // staging col (u16)

    for (int jt = 0; jt < ntiles; jt++) {
        const int j0 = jt << 6;
        // global loads (before barrier to hide latency)
        const uint4 k0v = *(const uint4*)(Kb + ((size_t)bh * SS + j0 + krow) * HDD + kch);
        const uint4 k1v = *(const uint4*)(Kb + ((size_t)bh * SS + j0 + 32 + krow) * HDD + kch);
        const uint4 v0v = *(const uint4*)(Vt + ((size_t)bh * HDD + krow) * SS + j0 + kch);
        const uint4 v1v = *(const uint4*)(Vt + ((size_t)bh * HDD + 32 + krow) * SS + j0 + kch);
        __syncthreads();                   // previous tile's MFMA reads done
        *(uint4*)&Ks[krow][kch] = k0v;
        *(uint4*)&Ks[32 + krow][kch] = k1v;
        *(uint4*)&Vs[krow][kch] = v0v;
        *(uint4*)&Vs[32 + krow][kch] = v1v;
        __syncthreads();

        // S = Q @ K^T  (16q x 64key per wave)
        f32x4 S[4];
        #pragma unroll
        for (int t = 0; t < 4; t++) {
            const bf16x8 b0 = *(const bf16x8*)&Ks[16 * t + li][quad * 8];
            const bf16x8 b1 = *(const bf16x8*)&Ks[16 * t + li][32 + quad * 8];
            f32x4 acc = {};
            acc = __builtin_amdgcn_mfma_f32_16x16x32_bf16(aQ0, b0, acc, 0, 0, 0);
            acc = __builtin_amdgcn_mfma_f32_16x16x32_bf16(aQ1, b1, acc, 0, 0, 0);
            S[t] = acc;
        }

        // causal mask on diagonal super-tile
        if (jt == ntiles - 1) {
            #pragma unroll
            for (int t = 0; t < 4; t++)
                #pragma unroll
                for (int r = 0; r < 4; r++)
                    if (16 * t + li > 16 * w + quad * 4 + r) S[t][r] = -1e30f;
        }

        // online softmax (rows = quad*4+r, reduce over 16 lanes li)
        float p[4][4];                     // [r][t]
        #pragma unroll
        for (int r = 0; r < 4; r++) {
            float mt = fmaxf(fmaxf(S[0][r], S[1][r]), fmaxf(S[2][r], S[3][r]));
            #pragma unroll
            for (int off = 1; off < 16; off <<= 1)
                mt = fmaxf(mt, __shfl_xor(mt, off));
            const float mnew = fmaxf(m_r[r], mt);
            const float alpha = __expf(m_r[r] - mnew);
            float ls = 0.f;
            #pragma unroll
            for (int t = 0; t < 4; t++) {
                p[r][t] = __expf(S[t][r] - mnew);
                ls += p[r][t];
            }
            #pragma unroll
            for (int off = 1; off < 16; off <<= 1)
                ls += __shfl_xor(ls, off);
            l_r[r] = l_r[r] * alpha + ls;
            m_r[r] = mnew;
            #pragma unroll
            for (int t2 = 0; t2 < 4; t2++) O[t2][r] *= alpha;
        }

        // P -> LDS (per-wave region; same-wave RAW, no barrier needed)
        #pragma unroll
        for (int r = 0; r < 4; r++)
            #pragma unroll
            for (int t = 0; t < 4; t++)
                Ps[w][quad * 4 + r][16 * t + li] = f2bf(p[r][t]);

        // O += P @ V
        const bf16x8 aP0 = *(const bf16x8*)&Ps[w][li][quad * 8];
        const bf16x8 aP1 = *(const bf16x8*)&Ps[w][li][32 + quad * 8];
        #pragma unroll
        for (int t2 = 0; t2 < 4; t2++) {
            const bf16x8 b0 = *(const bf16x8*)&Vs[16 * t2 + li][quad * 8];
            const bf16x8 b1 = *(const bf16x8*)&Vs[16 * t2 + li][32 + quad * 8];
            O[t2] = __builtin_amdgcn_mfma_f32_16x16x32_bf16(aP0, b0, O[t2], 0, 0, 0);
            O[t2] = __builtin_amdgcn_mfma_f32_16x16x32_bf16(aP1, b1, O[t2], 0, 0, 0);
        }
    }

    const int b = bh >> 4, h = bh & 15;
    #pragma unroll
    for (int r = 0; r < 4; r++) {
        const float inv = 1.f / l_r[r];
        const int row = q0 + 16 * w + quad * 4 + r;
        #pragma unroll
        for (int t2 = 0; t2 < 4; t2++)
            ctx[((size_t)b * SS + row) * DD + h * HDD + 16 * t2 + li] = O[t2][r] * inv;
    }
}

// ---------------- Output projection: ctx(fp32) @ Wo(fp32) -> out (fp32) ---------------
__global__ __launch_bounds__(256) void gemm_out(
    const float* __restrict__ Xf, const float* __restrict__ W, float* __restrict__ out)
{
    __shared__ float As[32][68];
    __shared__ float Bs[32][68];
    const int tid = threadIdx.x;
    const int m0 = blockIdx.y * 64;
    const int n0 = blockIdx.x * 64;
    const int tm = tid >> 4, tn = tid & 15;
    const int alr = tid >> 2;
    const int alc = (tid & 3) * 8;
    const int bkr = tid >> 3;
    const int bnc = (tid & 7) * 8;
    float acc[4][4] = {};

    for (int k0 = 0; k0 < DD; k0 += 32) {
        const float4 a0 = *(const float4*)&Xf[(size_t)(m0 + alr) * DD + k0 + alc];
        const float4 a1 = *(const float4*)&Xf[(size_t)(m0 + alr) * DD + k0 + alc + 4];
        const float4 b0 = *(const float4*)&W[(size_t)(k0 + bkr) * DD + n0 + bnc];
        const float4 b1 = *(const float4*)&W[(size_t)(k0 + bkr) * DD + n0 + bnc + 4];
        __syncthreads();
        As[alc + 0][alr] = a0.x; As[alc + 1][alr] = a0.y;
        As[alc + 2][alr] = a0.z; As[alc + 3][alr] = a0.w;
        As[alc + 4][alr] = a1.x; As[alc + 5][alr] = a1.y;
        As[alc + 6][alr] = a1.z; As[alc + 7][alr] = a1.w;
        Bs[bkr][bnc + 0] = b0.x; Bs[bkr][bnc + 1] = b0.y;
        Bs[bkr][bnc + 2] = b0.z; Bs[bkr][bnc + 3] = b0.w;
        Bs[bkr][bnc + 4] = b1.x; Bs[bkr][bnc + 5] = b1.y;
        Bs[bkr][bnc + 6] = b1.z; Bs[bkr][bnc + 7] = b1.w;
        __syncthreads();
        #pragma unroll
        for (int kk = 0; kk < 32; kk++) {
            const float4 a4 = *(const float4*)&As[kk][tm * 4];
            const float4 b4 = *(const float4*)&Bs[kk][tn * 4];
            const float ar[4] = {a4.x, a4.y, a4.z, a4.w};
            const float br[4] = {b4.x, b4.y, b4.z, b4.w};
            #pragma unroll
            for (int i = 0; i < 4; i++)
                #pragma unroll
                for (int j = 0; j < 4; j++)
                    acc[i][j] = fmaf(ar[i], br[j], acc[i][j]);
        }
    }

    #pragma unroll
    for (int r = 0; r < 4; r++) {
        const int m = m0 + tm * 4 + r;
        *(float4*)&out[(size_t)m * DD + n0 + tn * 4] =
            make_float4(acc[r][0], acc[r][1], acc[r][2], acc[r][3]);
    }
}

extern "C" void kernel_launch(void* const* d_in, const int* in_sizes, int n_in,
                              void* d_out, int out_size, void* d_ws, size_t ws_size,
                              hipStream_t stream) {
    const float* x  = (const float*)d_in[0];
    const float* Wq = (const float*)d_in[1];
    const float* Wk = (const float*)d_in[2];
    const float* Wv = (const float*)d_in[3];
    const float* Wo = (const float*)d_in[4];
    float* out = (float*)d_out;

    const size_t qkv_elems = (size_t)BB * HH * SS * HDD;  // 4,194,304
    u16* Qb = (u16*)d_ws;
    u16* Kb = Qb + qkv_elems;
    u16* Vtb = Kb + qkv_elems;
    float* ctx = (float*)(Vtb + qkv_elems);   // 25.2 + 16.8 = 42 MB total

    dim3 gg(DD / 64, (BB * SS) / 64), bb(256);
    hipLaunchKernelGGL(gemm_qk_bf16, gg, bb, 0, stream, x, Wq, Qb, 0.125f);
    hipLaunchKernelGGL(gemm_qk_bf16, gg, bb, 0, stream, x, Wk, Kb, 1.0f);
    hipLaunchKernelGGL(gemm_v_t,     gg, bb, 0, stream, x, Wv, Vtb);
    hipLaunchKernelGGL(attn_mfma, dim3(SS / 64, BB * HH), bb, 0, stream, Qb, Kb, Vtb, ctx);
    hipLaunchKernelGGL(gemm_out, gg, bb, 0, stream, ctx, Wo, out);
}